// Round 1
// baseline (81.621 us; speedup 1.0000x reference)
//
#include <hip/hip_runtime.h>
#include <math.h>

// Problem constants (fixed by setup_inputs: N=1024, H=W=256, B=64).
#define HCONST 256
#define WCONST 256
#define TILE_Y 32

// ---------------------------------------------------------------------------
// Kernel 1: per-gaussian separable factors.
//   fx[n][x] = exp(-ax*((x/255-mux)^2 - dxmin^2))
//   fy[n][y] = pred[n] * exp(-ay*((y/255-muy)^2 - dymin^2))
// The 1/(2*pi*sx*sy) prefactor cancels in g/max(g); the grid max of the
// separable product is the product of per-axis maxima, attained at the grid
// point nearest mu (grid step 1/255), so normalization folds into dmin^2.
// ---------------------------------------------------------------------------
__global__ __launch_bounds__(512) void prep_kernel(
    const float* __restrict__ pred,
    const float* __restrict__ nodes,   // (N,4): mux, muy, sx, sy
    float* __restrict__ Fx,
    float* __restrict__ Fy)
{
    const int n = blockIdx.x;
    const int t = threadIdx.x;
    const bool isY = (t >= WCONST);
    const int  i   = t & (WCONST - 1);

    const float4 nd = ((const float4*)nodes)[n];
    const float mu = isY ? nd.y : nd.x;
    const float s  = isY ? nd.w : nd.z;
    const float a  = 1.0f / (2.0f * s * s);

    const float step = 1.0f / 255.0f;
    const float d = i * step - mu;

    // nearest grid index to mu -> minimal |d| on this axis
    float ni = roundf(mu * 255.0f);
    ni = fminf(fmaxf(ni, 0.0f), 255.0f);
    const float dmin = ni * step - mu;

    float val = __expf(-a * (d * d - dmin * dmin));   // <= 1, ==1 at argmax
    if (isY) val *= pred[n];

    (isY ? Fy : Fx)[n * WCONST + i] = val;
}

// ---------------------------------------------------------------------------
// Kernel 2: bucket gaussian indices by batch (single block).
// offsets[B+1] exclusive prefix; indices[] gaussian ids grouped by batch.
// ---------------------------------------------------------------------------
__global__ __launch_bounds__(1024) void bucket_kernel(
    const int* __restrict__ batch_list, int N, int B,
    int* __restrict__ offsets, int* __restrict__ indices)
{
    __shared__ int cnt[64];
    __shared__ int base[65];
    const int t = threadIdx.x;

    if (t < B) cnt[t] = 0;
    __syncthreads();

    for (int n = t; n < N; n += blockDim.x)
        atomicAdd(&cnt[batch_list[n]], 1);
    __syncthreads();

    if (t == 0) {
        int acc = 0;
        for (int b = 0; b < B; ++b) { base[b] = acc; acc += cnt[b]; }
        base[B] = acc;
    }
    __syncthreads();

    if (t <= B) offsets[t] = base[t];
    if (t < B)  cnt[t] = base[t];   // reuse as running cursor
    __syncthreads();

    for (int n = t; n < N; n += blockDim.x) {
        const int b   = batch_list[n];
        const int pos = atomicAdd(&cnt[b], 1);
        indices[pos] = n;
    }
}

// ---------------------------------------------------------------------------
// Kernel 3: segment-summed rank-1 accumulate.
// grid = B * (H/TILE_Y) blocks, 256 threads (one x-column each).
// Each thread keeps TILE_Y fp32 accumulators in registers; per gaussian:
// one coalesced fx load + TILE_Y broadcast fy loads + TILE_Y FMAs.
// Every output element is written exactly once (no pre-zero needed).
// ---------------------------------------------------------------------------
__global__ __launch_bounds__(256) void accum_kernel(
    const float* __restrict__ Fx, const float* __restrict__ Fy,
    const int* __restrict__ offsets, const int* __restrict__ indices,
    float* __restrict__ out)
{
    const int tiles = HCONST / TILE_Y;           // 8
    const int b  = blockIdx.x / tiles;
    const int ty = blockIdx.x % tiles;
    const int y0 = ty * TILE_Y;
    const int x  = threadIdx.x;

    float acc[TILE_Y];
#pragma unroll
    for (int yy = 0; yy < TILE_Y; ++yy) acc[yy] = 0.0f;

    const int g0 = offsets[b];
    const int g1 = offsets[b + 1];
    for (int g = g0; g < g1; ++g) {
        const int n = indices[g];
        const float fxv = Fx[n * WCONST + x];
        const float* fy = &Fy[n * HCONST + y0];
#pragma unroll
        for (int yy = 0; yy < TILE_Y; ++yy)
            acc[yy] = fmaf(fy[yy], fxv, acc[yy]);
    }

    float* o = out + ((size_t)b * HCONST + y0) * WCONST + x;
#pragma unroll
    for (int yy = 0; yy < TILE_Y; ++yy)
        o[yy * WCONST] = acc[yy];
}

// ---------------------------------------------------------------------------
extern "C" void kernel_launch(void* const* d_in, const int* in_sizes, int n_in,
                              void* d_out, int out_size, void* d_ws, size_t ws_size,
                              hipStream_t stream) {
    const float* pred       = (const float*)d_in[0];
    const float* nodes      = (const float*)d_in[1];
    const int*   batch_list = (const int*)d_in[2];

    const int N = in_sizes[0];                    // 1024
    const int B = out_size / (HCONST * WCONST);   // 64

    float* out = (float*)d_out;

    // Workspace layout: Fx[N*256] | Fy[N*256] | offsets[B+1] | indices[N]
    float* Fx = (float*)d_ws;
    float* Fy = Fx + (size_t)N * WCONST;
    int* offsets = (int*)(Fy + (size_t)N * HCONST);
    int* indices = offsets + (B + 1);

    prep_kernel<<<N, 512, 0, stream>>>(pred, nodes, Fx, Fy);
    bucket_kernel<<<1, 1024, 0, stream>>>(batch_list, N, B, offsets, indices);
    accum_kernel<<<B * (HCONST / TILE_Y), 256, 0, stream>>>(Fx, Fy, offsets, indices, out);
}